// Round 1
// baseline (501.329 us; speedup 1.0000x reference)
//
#include <hip/hip_runtime.h>

#define D_ 64
#define H_ 128
#define W_ 128
#define VOL (D_*H_*W_)   // 1048576 = 1<<20
#define NF 4             // {pred,target} x {b0,b1}
#define LARGEF 1e8f

__device__ __forceinline__ bool maskv(float v, int which) {
  // which==0: pred mask = sigmoid(v)>0.5 <=> v>0 ; which==1: target != 0
  return which ? (v != 0.0f) : (v > 0.0f);
}

// ---- build d2 seed: 0 at surface voxels, 1e8 elsewhere. Also zero acc. ----
__global__ __launch_bounds__(256) void k_init(const float* __restrict__ pred,
                                              const float* __restrict__ targ,
                                              float* __restrict__ d2,
                                              double* __restrict__ acc) {
  int idx = blockIdx.x * 256 + threadIdx.x;          // [0, NF*VOL)
  if (idx < 2) acc[idx] = 0.0;                       // ws is poisoned each call
  int f = idx >> 20;
  int v = idx & (VOL - 1);
  int b = f >> 1, which = f & 1;
  const float* __restrict__ src = (which ? targ : pred) + (size_t)b * VOL;
  int z = v >> 14, y = (v >> 7) & 127, x = v & 127;
  bool m = maskv(src[v], which);
  float out = LARGEF;
  if (m) {
    // eroded = m && all 6 in-bounds neighbors masked (OOB neighbor -> false)
    bool er = true;
    er = er && (z > 0)      && maskv(src[v - H_*W_], which);
    er = er && (z < D_ - 1) && maskv(src[v + H_*W_], which);
    er = er && (y > 0)      && maskv(src[v - W_], which);
    er = er && (y < H_ - 1) && maskv(src[v + W_], which);
    er = er && (x > 0)      && maskv(src[v - 1], which);
    er = er && (x < W_ - 1) && maskv(src[v + 1], which);
    out = er ? LARGEF : 0.0f;                        // surface = m && !eroded
  }
  d2[idx] = out;
}

// ---- EDT pass along z (axis 0). Block: 64 x-lanes x 4 waves, tile [64z][64x]
__global__ __launch_bounds__(256) void k_edt_z(float* __restrict__ d2) {
  __shared__ float tile[D_][64];
  int f = blockIdx.z, y = blockIdx.y, x0 = blockIdx.x << 6;
  int tx = threadIdx.x & 63, tw = threadIdx.x >> 6;
  float* base = d2 + (f << 20) + (y << 7) + x0;
  for (int z = tw; z < D_; z += 4)
    tile[z][tx] = base[(z << 14) + tx];
  __syncthreads();
  for (int i = tw; i < D_; i += 4) {
    float best = tile[i][tx];                        // j==i term
    for (int j = 0; j < D_; ++j) {
      float diff = (float)(i - j);
      best = fminf(best, tile[j][tx] + diff * diff);
    }
    base[(i << 14) + tx] = best;                     // in-place: line fully in LDS
  }
}

// ---- EDT pass along y (axis 1). tile [128y][64x]
__global__ __launch_bounds__(256) void k_edt_y(float* __restrict__ d2) {
  __shared__ float tile[H_][64];
  int f = blockIdx.z, z = blockIdx.y, x0 = blockIdx.x << 6;
  int tx = threadIdx.x & 63, tw = threadIdx.x >> 6;
  float* base = d2 + (f << 20) + (z << 14) + x0;
  for (int y = tw; y < H_; y += 4)
    tile[y][tx] = base[(y << 7) + tx];
  __syncthreads();
  for (int i = tw; i < H_; i += 4) {
    float best = tile[i][tx];
    for (int j = 0; j < H_; ++j) {
      float diff = (float)(i - j);
      best = fminf(best, tile[j][tx] + diff * diff);
    }
    base[(i << 7) + tx] = best;
  }
}

// ---- EDT pass along x (axis 2). 2 contiguous lines per 256-thread block.
__global__ __launch_bounds__(256) void k_edt_x(float* __restrict__ d2) {
  __shared__ float line[2][W_];
  int ty = threadIdx.x >> 7;                         // line within block
  int tx = threadIdx.x & 127;
  int lid = (blockIdx.x << 1) + ty;                  // global line id
  float* base = d2 + (size_t)lid * W_;
  line[ty][tx] = base[tx];
  __syncthreads();
  float best = line[ty][tx];
  for (int j = 0; j < W_; ++j) {
    float diff = (float)(tx - j);
    best = fminf(best, line[ty][j] + diff * diff);   // uniform j -> LDS broadcast
  }
  base[tx] = best;
}

// ---- smooth-L1 partial reduction per sample, double accumulation ----
__global__ __launch_bounds__(256) void k_reduce(const float* __restrict__ d2,
                                               double* __restrict__ acc) {
  int b = blockIdx.y;
  const float* dp = d2 + ((size_t)(b * 2 + 0) << 20);
  const float* dt = d2 + ((size_t)(b * 2 + 1) << 20);
  double s = 0.0;
  for (int v = blockIdx.x * 256 + threadIdx.x; v < VOL; v += gridDim.x * 256) {
    float a = sqrtf(dp[v]), c = sqrtf(dt[v]);
    float d = a - c, ad = fabsf(d);
    s += (double)(ad < 1.0f ? 0.5f * d * d : ad - 0.5f);
  }
  for (int o = 32; o > 0; o >>= 1) s += __shfl_down(s, o);
  __shared__ double wsum[4];
  if ((threadIdx.x & 63) == 0) wsum[threadIdx.x >> 6] = s;
  __syncthreads();
  if (threadIdx.x == 0)
    atomicAdd(&acc[b], wsum[0] + wsum[1] + wsum[2] + wsum[3]);
}

__global__ void k_final(const double* __restrict__ acc, float* __restrict__ out) {
  if (threadIdx.x == 0 && blockIdx.x == 0)
    out[0] = (float)(0.5 * (acc[0] / (double)VOL + acc[1] / (double)VOL));
}

extern "C" void kernel_launch(void* const* d_in, const int* in_sizes, int n_in,
                              void* d_out, int out_size, void* d_ws, size_t ws_size,
                              hipStream_t stream) {
  const float* pred = (const float*)d_in[0];
  const float* targ = (const float*)d_in[1];
  float*  d2  = (float*)d_ws;
  double* acc = (double*)((char*)d_ws + (size_t)NF * VOL * sizeof(float));
  float*  out = (float*)d_out;

  k_init <<<NF * VOL / 256, 256, 0, stream>>>(pred, targ, d2, acc);
  k_edt_z<<<dim3(W_ / 64, H_, NF), 256, 0, stream>>>(d2);
  k_edt_y<<<dim3(W_ / 64, D_, NF), 256, 0, stream>>>(d2);
  k_edt_x<<<NF * D_ * H_ / 2, 256, 0, stream>>>(d2);
  k_reduce<<<dim3(256, 2), 256, 0, stream>>>(d2, acc);
  k_final<<<1, 64, 0, stream>>>(acc, out);
}

// Round 4
// 221.376 us; speedup vs baseline: 2.2646x; 2.2646x over previous
//
#include <hip/hip_runtime.h>

#define D_ 64
#define H_ 128
#define W_ 128
#define VOL (D_*H_*W_)   // 1048576 = 1<<20
#define NF 4             // {pred,target} x {b0,b1}
#define LARGEF 1e8f

__device__ __forceinline__ bool maskv(float v, int which) {
  // which==0: pred mask = sigmoid(v)>0.5 <=> v>0 ; which==1: target != 0
  return which ? (v != 0.0f) : (v > 0.0f);
}

// ---- build d2 seed: 0 at surface voxels, 1e8 elsewhere. Also zero acc. ----
__global__ __launch_bounds__(256) void k_init(const float* __restrict__ pred,
                                              const float* __restrict__ targ,
                                              float* __restrict__ d2,
                                              double* __restrict__ acc) {
  int idx = blockIdx.x * 256 + threadIdx.x;          // [0, NF*VOL)
  if (idx < 2) acc[idx] = 0.0;                       // ws is poisoned each call
  int f = idx >> 20;
  int v = idx & (VOL - 1);
  int b = f >> 1, which = f & 1;
  const float* __restrict__ src = (which ? targ : pred) + (size_t)b * VOL;
  int z = v >> 14, y = (v >> 7) & 127, x = v & 127;
  bool m = maskv(src[v], which);
  float out = LARGEF;
  if (m) {
    bool er = true;
    er = er && (z > 0)      && maskv(src[v - H_*W_], which);
    er = er && (z < D_ - 1) && maskv(src[v + H_*W_], which);
    er = er && (y > 0)      && maskv(src[v - W_], which);
    er = er && (y < H_ - 1) && maskv(src[v + W_], which);
    er = er && (x > 0)      && maskv(src[v - 1], which);
    er = er && (x < W_ - 1) && maskv(src[v + 1], which);
    out = er ? LARGEF : 0.0f;                        // surface = m && !eroded
  }
  d2[idx] = out;
}

// ---- EDT z-pass. tile [64z][64x]; wave w register-blocks i in [16w,16w+16)
__global__ __launch_bounds__(256) void k_edt_z(float* __restrict__ d2) {
  __shared__ float tile[D_][64];
  int f = blockIdx.z, y = blockIdx.y, x0 = blockIdx.x << 6;
  int tx = threadIdx.x & 63, tw = threadIdx.x >> 6;
  float* base = d2 + (f << 20) + (y << 7) + x0;
  for (int z = tw; z < D_; z += 4)
    tile[z][tx] = base[(z << 14) + tx];
  __syncthreads();
  const int R = 16;
  float best[R], fi[R];
  float fbase = (float)(tw * R);
  #pragma unroll
  for (int u = 0; u < R; ++u) { best[u] = LARGEF; fi[u] = fbase + (float)u; }
  for (int j = 0; j < D_; ++j) {
    float t = tile[j][tx];                           // one LDS read, R updates
    float fj = (float)j;
    #pragma unroll
    for (int u = 0; u < R; ++u) {
      float diff = fi[u] - fj;
      best[u] = fminf(best[u], __builtin_fmaf(diff, diff, t));
    }
  }
  #pragma unroll
  for (int u = 0; u < R; ++u)
    base[((tw * R + u) << 14) + tx] = best[u];
}

// ---- EDT y-pass. tile [128y][64x]; wave w register-blocks i in [32w,32w+32)
__global__ __launch_bounds__(256) void k_edt_y(float* __restrict__ d2) {
  __shared__ float tile[H_][64];
  int f = blockIdx.z, z = blockIdx.y, x0 = blockIdx.x << 6;
  int tx = threadIdx.x & 63, tw = threadIdx.x >> 6;
  float* base = d2 + (f << 20) + (z << 14) + x0;
  for (int y = tw; y < H_; y += 4)
    tile[y][tx] = base[(y << 7) + tx];
  __syncthreads();
  const int R = 32;
  float best[R], fi[R];
  float fbase = (float)(tw * R);
  #pragma unroll
  for (int u = 0; u < R; ++u) { best[u] = LARGEF; fi[u] = fbase + (float)u; }
  for (int j = 0; j < H_; ++j) {
    float t = tile[j][tx];
    float fj = (float)j;
    #pragma unroll
    for (int u = 0; u < R; ++u) {
      float diff = fi[u] - fj;
      best[u] = fminf(best[u], __builtin_fmaf(diff, diff, t));
    }
  }
  #pragma unroll
  for (int u = 0; u < R; ++u)
    base[((tw * R + u) << 7) + tx] = best[u];
}

// ---- EDT x-pass. 64 contiguous lines per block; lane = line (padded LDS),
// wave w register-blocks i in [32w,32w+32). LDS-staged coalesced writeback.
__global__ __launch_bounds__(256) void k_edt_x(float* __restrict__ d2) {
  __shared__ float tile[64][W_ + 1];                 // +1 pad: 2-way banks = free
  float* base = d2 + (size_t)blockIdx.x * 64 * W_;
  for (int idx = threadIdx.x; idx < 64 * W_; idx += 256)
    tile[idx >> 7][idx & 127] = base[idx];
  __syncthreads();
  int lane = threadIdx.x & 63, tw = threadIdx.x >> 6;
  const int R = 32;
  float best[R], fi[R];
  float fbase = (float)(tw * R);
  #pragma unroll
  for (int u = 0; u < R; ++u) { best[u] = LARGEF; fi[u] = fbase + (float)u; }
  for (int j = 0; j < W_; ++j) {
    float t = tile[lane][j];
    float fj = (float)j;
    #pragma unroll
    for (int u = 0; u < R; ++u) {
      float diff = fi[u] - fj;
      best[u] = fminf(best[u], __builtin_fmaf(diff, diff, t));
    }
  }
  __syncthreads();                                   // all reads done before overwrite
  #pragma unroll
  for (int u = 0; u < R; ++u)
    tile[lane][tw * R + u] = best[u];
  __syncthreads();
  for (int idx = threadIdx.x; idx < 64 * W_; idx += 256)
    base[idx] = tile[idx >> 7][idx & 127];
}

// ---- smooth-L1 partial reduction per sample, double accumulation ----
__global__ __launch_bounds__(256) void k_reduce(const float* __restrict__ d2,
                                               double* __restrict__ acc) {
  int b = blockIdx.y;
  const float* dp = d2 + ((size_t)(b * 2 + 0) << 20);
  const float* dt = d2 + ((size_t)(b * 2 + 1) << 20);
  double s = 0.0;
  for (int v = blockIdx.x * 256 + threadIdx.x; v < VOL; v += gridDim.x * 256) {
    float a = sqrtf(dp[v]), c = sqrtf(dt[v]);
    float d = a - c, ad = fabsf(d);
    s += (double)(ad < 1.0f ? 0.5f * d * d : ad - 0.5f);
  }
  for (int o = 32; o > 0; o >>= 1) s += __shfl_down(s, o);
  __shared__ double wsum[4];
  if ((threadIdx.x & 63) == 0) wsum[threadIdx.x >> 6] = s;
  __syncthreads();
  if (threadIdx.x == 0)
    atomicAdd(&acc[b], wsum[0] + wsum[1] + wsum[2] + wsum[3]);
}

__global__ void k_final(const double* __restrict__ acc, float* __restrict__ out) {
  if (threadIdx.x == 0 && blockIdx.x == 0)
    out[0] = (float)(0.5 * (acc[0] / (double)VOL + acc[1] / (double)VOL));
}

extern "C" void kernel_launch(void* const* d_in, const int* in_sizes, int n_in,
                              void* d_out, int out_size, void* d_ws, size_t ws_size,
                              hipStream_t stream) {
  const float* pred = (const float*)d_in[0];
  const float* targ = (const float*)d_in[1];
  float*  d2  = (float*)d_ws;
  double* acc = (double*)((char*)d_ws + (size_t)NF * VOL * sizeof(float));
  float*  out = (float*)d_out;

  k_init <<<NF * VOL / 256, 256, 0, stream>>>(pred, targ, d2, acc);
  k_edt_z<<<dim3(W_ / 64, H_, NF), 256, 0, stream>>>(d2);
  k_edt_y<<<dim3(W_ / 64, D_, NF), 256, 0, stream>>>(d2);
  k_edt_x<<<NF * D_ * H_ / 64, 256, 0, stream>>>(d2);
  k_reduce<<<dim3(256, 2), 256, 0, stream>>>(d2, acc);
  k_final<<<1, 64, 0, stream>>>(acc, out);
}

// Round 5
// 161.570 us; speedup vs baseline: 3.1029x; 1.3702x over previous
//
#include <hip/hip_runtime.h>

#define D_ 64
#define H_ 128
#define W_ 128
#define VOL (D_*H_*W_)   // 1048576 = 1<<20
#define NF 4             // {pred,target} x {b0,b1}
#define LARGEF 1e8f

__device__ __forceinline__ bool maskv(float v, int which) {
  // which==0: pred mask = sigmoid(v)>0.5 <=> v>0 ; which==1: target != 0
  return which ? (v != 0.0f) : (v > 0.0f);
}

// ---- build d2 seed: 0 at surface voxels, 1e8 elsewhere. Also zero acc. ----
__global__ __launch_bounds__(256) void k_init(const float* __restrict__ pred,
                                              const float* __restrict__ targ,
                                              float* __restrict__ d2,
                                              double* __restrict__ acc) {
  int idx = blockIdx.x * 256 + threadIdx.x;          // [0, NF*VOL)
  if (idx < 2) acc[idx] = 0.0;                       // ws is poisoned each call
  int f = idx >> 20;
  int v = idx & (VOL - 1);
  int b = f >> 1, which = f & 1;
  const float* __restrict__ src = (which ? targ : pred) + (size_t)b * VOL;
  int z = v >> 14, y = (v >> 7) & 127, x = v & 127;
  bool m = maskv(src[v], which);
  float out = LARGEF;
  if (m) {
    bool er = true;
    er = er && (z > 0)      && maskv(src[v - H_*W_], which);
    er = er && (z < D_ - 1) && maskv(src[v + H_*W_], which);
    er = er && (y > 0)      && maskv(src[v - W_], which);
    er = er && (y < H_ - 1) && maskv(src[v + W_], which);
    er = er && (x > 0)      && maskv(src[v - 1], which);
    er = er && (x < W_ - 1) && maskv(src[v + 1], which);
    out = er ? LARGEF : 0.0f;                        // surface = m && !eroded
  }
  d2[idx] = out;
}

// ---- z-pass: seeds are binary {0,1e8} -> O(n) two-scan nearest-surface.
// One thread per (f,y,x) column; fwd distances staged in LDS u16; in-place.
__global__ __launch_bounds__(256) void k_zscan(float* __restrict__ d2) {
  __shared__ unsigned short fwd[D_][256];
  int g = blockIdx.x * 256 + threadIdx.x;            // 65536 columns
  int f = g >> 14, yx = g & 16383;
  float* base = d2 + (f << 20) + yx;
  int d = 16384;
  #pragma unroll 4
  for (int z = 0; z < D_; ++z) {
    float s = base[z << 14];                         // coalesced plane read
    d = (s == 0.0f) ? 0 : min(d + 1, 16384);
    fwd[z][threadIdx.x] = (unsigned short)d;         // u16: 2-way banks = free
  }
  int dd = 16384;                                    // column is thread-private: no sync
  #pragma unroll 4
  for (int z = D_ - 1; z >= 0; --z) {
    int fv = fwd[z][threadIdx.x];
    dd = (fv == 0) ? 0 : min(dd + 1, 16384);
    int r = min(fv, dd);
    base[z << 14] = (r >= 16384) ? LARGEF : (float)(r * r);
  }
}

// ---- EDT y-pass. 512 thr (8 waves), tile[j][x]+j^2 folded at stage.
// wave w register-blocks i in [16w,16w+16); 2 VALU/pair: fmin(fma(-2j,i,t')).
__global__ __launch_bounds__(512) void k_edt_y(float* __restrict__ d2) {
  __shared__ float tile[H_][64];
  int f = blockIdx.z, z = blockIdx.y, x0 = blockIdx.x << 6;
  int tx = threadIdx.x & 63, tw = threadIdx.x >> 6;  // tw in [0,8)
  float* base = d2 + (f << 20) + (z << 14) + x0;
  for (int t = threadIdx.x; t < H_ * 64; t += 512) {
    int j = t >> 6, xx = t & 63;
    tile[j][xx] = base[(j << 7) + xx] + (float)(j * j);
  }
  __syncthreads();
  const int R = 16;
  float best[R], fi[R];
  float fbase = (float)(tw * R);
  #pragma unroll
  for (int u = 0; u < R; ++u) { best[u] = 3.0e8f; fi[u] = fbase + (float)u; }
  #pragma unroll 2
  for (int j = 0; j < H_; ++j) {
    float t = tile[j][tx];
    float m2j = -2.0f * (float)j;
    #pragma unroll
    for (int u = 0; u < R; ++u)
      best[u] = fminf(best[u], __builtin_fmaf(m2j, fi[u], t));
  }
  #pragma unroll
  for (int u = 0; u < R; ++u)
    base[((tw * R + u) << 7) + tx] = best[u] + fi[u] * fi[u];
}

// ---- EDT x-pass. 64 lines/block (lane = line, padded LDS), 8 waves x R=16.
__global__ __launch_bounds__(512) void k_edt_x(float* __restrict__ d2) {
  __shared__ float tile[64][W_ + 1];                 // +1 pad: 2-way banks = free
  float* base = d2 + (size_t)blockIdx.x * 64 * W_;
  for (int t = threadIdx.x; t < 64 * W_; t += 512) {
    int r = t >> 7, c = t & 127;
    tile[r][c] = base[t] + (float)(c * c);           // fold +j^2
  }
  __syncthreads();
  int lane = threadIdx.x & 63, tw = threadIdx.x >> 6;
  const int R = 16;
  float best[R], fi[R];
  float fbase = (float)(tw * R);
  #pragma unroll
  for (int u = 0; u < R; ++u) { best[u] = 3.0e8f; fi[u] = fbase + (float)u; }
  #pragma unroll 2
  for (int j = 0; j < W_; ++j) {
    float t = tile[lane][j];
    float m2j = -2.0f * (float)j;
    #pragma unroll
    for (int u = 0; u < R; ++u)
      best[u] = fminf(best[u], __builtin_fmaf(m2j, fi[u], t));
  }
  __syncthreads();                                   // all reads done before overwrite
  #pragma unroll
  for (int u = 0; u < R; ++u)
    tile[lane][tw * R + u] = best[u] + fi[u] * fi[u];
  __syncthreads();
  for (int t = threadIdx.x; t < 64 * W_; t += 512)
    base[t] = tile[t >> 7][t & 127];
}

// ---- smooth-L1 partial reduction per sample, double accumulation ----
__global__ __launch_bounds__(256) void k_reduce(const float* __restrict__ d2,
                                               double* __restrict__ acc) {
  int b = blockIdx.y;
  const float* dp = d2 + ((size_t)(b * 2 + 0) << 20);
  const float* dt = d2 + ((size_t)(b * 2 + 1) << 20);
  double s = 0.0;
  for (int v = blockIdx.x * 256 + threadIdx.x; v < VOL; v += gridDim.x * 256) {
    float a = sqrtf(dp[v]), c = sqrtf(dt[v]);
    float d = a - c, ad = fabsf(d);
    s += (double)(ad < 1.0f ? 0.5f * d * d : ad - 0.5f);
  }
  for (int o = 32; o > 0; o >>= 1) s += __shfl_down(s, o);
  __shared__ double wsum[4];
  if ((threadIdx.x & 63) == 0) wsum[threadIdx.x >> 6] = s;
  __syncthreads();
  if (threadIdx.x == 0)
    atomicAdd(&acc[b], wsum[0] + wsum[1] + wsum[2] + wsum[3]);
}

__global__ void k_final(const double* __restrict__ acc, float* __restrict__ out) {
  if (threadIdx.x == 0 && blockIdx.x == 0)
    out[0] = (float)(0.5 * (acc[0] / (double)VOL + acc[1] / (double)VOL));
}

extern "C" void kernel_launch(void* const* d_in, const int* in_sizes, int n_in,
                              void* d_out, int out_size, void* d_ws, size_t ws_size,
                              hipStream_t stream) {
  const float* pred = (const float*)d_in[0];
  const float* targ = (const float*)d_in[1];
  float*  d2  = (float*)d_ws;
  double* acc = (double*)((char*)d_ws + (size_t)NF * VOL * sizeof(float));
  float*  out = (float*)d_out;

  k_init <<<NF * VOL / 256, 256, 0, stream>>>(pred, targ, d2, acc);
  k_zscan<<<NF * H_ * W_ / 256, 256, 0, stream>>>(d2);
  k_edt_y<<<dim3(2, D_, NF), 512, 0, stream>>>(d2);
  k_edt_x<<<NF * D_ * H_ / 64, 512, 0, stream>>>(d2);
  k_reduce<<<dim3(256, 2), 256, 0, stream>>>(d2, acc);
  k_final<<<1, 64, 0, stream>>>(acc, out);
}